// Round 1
// baseline (322.298 us; speedup 1.0000x reference)
//
#include <hip/hip_runtime.h>

constexpr int B_ = 4, C_ = 5, H_ = 96, W_ = 96;
constexpr int N_ = H_ * W_;      // 9216
constexpr int NPT = N_ / 256;    // 36 elements per thread
constexpr int NJ = NPT / 4;      // 9 float4 per thread

// ---------------- kernel 1: 1x1-conv projections q,k -> ws as [B][C][N] ----
__global__ __launch_bounds__(256) void proj_qk(
    const float* __restrict__ x,
    const float* __restrict__ wq, const float* __restrict__ bq,
    const float* __restrict__ wk, const float* __restrict__ bk,
    float* __restrict__ q, float* __restrict__ k)
{
    int idx = blockIdx.x * 256 + threadIdx.x;   // over B*N
    if (idx >= B_ * N_) return;
    int b = idx / N_;
    int n = idx - b * N_;
    float xi[C_];
#pragma unroll
    for (int i = 0; i < C_; ++i) xi[i] = x[(size_t)(b * C_ + i) * N_ + n];
#pragma unroll
    for (int c = 0; c < C_; ++c) {
        float aq = bq[c], ak = bk[c];
#pragma unroll
        for (int i = 0; i < C_; ++i) {
            aq = fmaf(wq[c * C_ + i], xi[i], aq);
            ak = fmaf(wk[c * C_ + i], xi[i], ak);
        }
        q[(size_t)(b * C_ + c) * N_ + n] = aq;
        k[(size_t)(b * C_ + c) * N_ + n] = ak;
    }
}

// ---------------- kernel 2: one block per output row; fused energy+softmax -
__global__ __launch_bounds__(256) void attn_row(
    const float* __restrict__ q, const float* __restrict__ k,
    float* __restrict__ out)
{
    const int row = blockIdx.x;          // b*N + n
    const int b = row / N_;
    const int n = row - b * N_;
    const int tid = threadIdx.x;

    // q vector for this row (5 scalars, broadcast across the block)
    float qv[C_];
#pragma unroll
    for (int c = 0; c < C_; ++c) qv[c] = q[(size_t)(b * C_ + c) * N_ + n];

    const float* kb = k + (size_t)b * C_ * N_;

    // energy row lives entirely in registers: 9 x float4 per thread
    float4 e[NJ];
    float lmax = -3.4e38f;
#pragma unroll
    for (int j = 0; j < NJ; ++j) {
        const int m4 = (j * 256 + tid) * 4;
        float4 acc = make_float4(0.f, 0.f, 0.f, 0.f);
#pragma unroll
        for (int c = 0; c < C_; ++c) {
            const float4 kv = *reinterpret_cast<const float4*>(kb + (size_t)c * N_ + m4);
            acc.x = fmaf(qv[c], kv.x, acc.x);
            acc.y = fmaf(qv[c], kv.y, acc.y);
            acc.z = fmaf(qv[c], kv.z, acc.z);
            acc.w = fmaf(qv[c], kv.w, acc.w);
        }
        e[j] = acc;
        lmax = fmaxf(lmax, fmaxf(fmaxf(acc.x, acc.y), fmaxf(acc.z, acc.w)));
    }

    __shared__ float redmax[4];
    __shared__ float redsum[4];

    // block max (4 waves of 64)
#pragma unroll
    for (int off = 32; off >= 1; off >>= 1)
        lmax = fmaxf(lmax, __shfl_xor(lmax, off, 64));
    const int wv = tid >> 6;
    if ((tid & 63) == 0) redmax[wv] = lmax;
    __syncthreads();
    const float rmax = fmaxf(fmaxf(redmax[0], redmax[1]),
                             fmaxf(redmax[2], redmax[3]));

    // exp + block sum
    float lsum = 0.f;
#pragma unroll
    for (int j = 0; j < NJ; ++j) {
        e[j].x = __expf(e[j].x - rmax);
        e[j].y = __expf(e[j].y - rmax);
        e[j].z = __expf(e[j].z - rmax);
        e[j].w = __expf(e[j].w - rmax);
        lsum += (e[j].x + e[j].y) + (e[j].z + e[j].w);
    }
#pragma unroll
    for (int off = 32; off >= 1; off >>= 1)
        lsum += __shfl_xor(lsum, off, 64);
    if ((tid & 63) == 0) redsum[wv] = lsum;
    __syncthreads();
    const float inv = 1.f / ((redsum[0] + redsum[1]) + (redsum[2] + redsum[3]));

    // scaled store, float4-coalesced
    float* orow = out + (size_t)row * N_;
#pragma unroll
    for (int j = 0; j < NJ; ++j) {
        const int m4 = (j * 256 + tid) * 4;
        const float4 o = make_float4(e[j].x * inv, e[j].y * inv,
                                     e[j].z * inv, e[j].w * inv);
        *reinterpret_cast<float4*>(orow + m4) = o;
    }
}

extern "C" void kernel_launch(void* const* d_in, const int* in_sizes, int n_in,
                              void* d_out, int out_size, void* d_ws, size_t ws_size,
                              hipStream_t stream)
{
    const float* x  = (const float*)d_in[0];
    const float* wq = (const float*)d_in[1];
    const float* bq = (const float*)d_in[2];
    const float* wk = (const float*)d_in[3];
    const float* bk = (const float*)d_in[4];
    float* out = (float*)d_out;

    float* q = (float*)d_ws;                       // [B][C][N]
    float* k = q + (size_t)B_ * C_ * N_;           // [B][C][N]

    proj_qk<<<(B_ * N_ + 255) / 256, 256, 0, stream>>>(x, wq, bq, wk, bk, q, k);
    attn_row<<<B_ * N_, 256, 0, stream>>>(q, k, out);
}